// Round 12
// baseline (195.808 us; speedup 1.0000x reference)
//
#include <hip/hip_runtime.h>

#define RES    28
#define DIMC   384
#define NHEAD  8
#define HDIM   48
#define DPAD   64
#define NPIX   784
#define NB     16
#define SC2    0.20823294f    // 48^-0.5 * log2(e)
#define LOG2E  1.44269504f

typedef short bf16x8 __attribute__((ext_vector_type(8)));
typedef float f32x4  __attribute__((ext_vector_type(4)));

__device__ __forceinline__ short f2bf(float x) {
  union { float f; unsigned u; } v; v.f = x;
  return (short)((v.u + 0x7FFFu + ((v.u >> 16) & 1u)) >> 16);   // RNE
}
__device__ __forceinline__ unsigned pk_rne(float a, float b) {
  union { float f; unsigned u; } x, y; x.f = a; y.f = b;
  return __builtin_amdgcn_perm(y.u + 0x7FFFu + ((y.u >> 16) & 1u),
                               x.u + 0x7FFFu + ((x.u >> 16) & 1u), 0x07060302u);
}
__device__ __forceinline__ unsigned cvtpk(float a, float b) {   // lo=bf16(a), hi=bf16(b), RNE
  unsigned r;
  asm("v_cvt_pk_bf16_f32 %0, %1, %2" : "=v"(r) : "v"(a), "v"(b));
  return r;
}
__device__ __forceinline__ float blo(unsigned u) { union { unsigned u; float f; } v; v.u = u << 16; return v.f; }
__device__ __forceinline__ float bhi(unsigned u) { union { unsigned u; float f; } v; v.u = u & 0xFFFF0000u; return v.f; }

// ======================= FRAGMENT-PACKED LAYOUTS (R6) =======================
// Xf [b][pxt 49][ks 12][lane][8] : X[b][px=pxt*16+(l&15)][ch=ks*32+(l>>4)*8+e]
// Kf [bh][chunk 25][frag 4][lane][8] : frag=kh*2+dh ->
//      K[bh][k=chunk*32+kh*16+(l&15)][d=dh*32+(l>>4)*8+e]  (d48-63, k784-799 zero)
// Vf [bh][chunk 25][frag 3][lane][8] : V[bh][d=frag*16+(l&15)][k=chunk*32+(l>>4)*8+e]
// Bt3[h][qt 49][chunk 25][lane][8] : shorts 0-3 = bias[q=qt*16+(l&15)][k=c*32+qq*4+u],
//      shorts 4-7 = k+16; k>=784 slots hold bf16(-1e30) -> p = 0 (uniform tail).
//      R8: this IS the QK C-fragment layout (col=lane&15=q, row=qq*4+reg) -> C-init.
// AOf[b][pxt 49][ks 12][lane][8] : attn output (proj reads it)
// Qb row-major (b,h,784,64) padded; R8: Q pre-scaled by SC2 at qkv epilogue.
// R12: qkv stages 2 K-steps per LDS buffer -> 28 MFMAs per barrier (was 14),
//      barrier count 13 -> 7 (m97 lesson: barrier drain dominates shallow loops).

// ================= prep: transpose->Xf, pack W, bias->Bt3, zeros ==========
__global__ __launch_bounds__(256) void prep_kernel(
    const float* __restrict__ ll, const float* __restrict__ ha,
    const float* __restrict__ qw, const float* __restrict__ kvw, const float* __restrict__ pw,
    const float* __restrict__ biases,
    short* __restrict__ Xll, short* __restrict__ Xha,
    short* __restrict__ Wf2, short* __restrict__ Wfp,
    short* __restrict__ Bt3, short* __restrict__ Qb,
    short* __restrict__ Kf, short* __restrict__ Vf)
{
  __shared__ __align__(16) short sT[64][72];
  __shared__ float sB[NPIX];
  const int bid = blockIdx.x, t = threadIdx.x;

  if (bid < 2496) {               // ---- transpose (b,c,pix) f32 -> Xf frag layout ----
    const int px = bid % 13, cb = (bid / 13) % 6, zz = bid / 78;
    const int which = zz >> 4, b = zz & 15;
    const float* X = (which ? ha : ll) + (size_t)b * DIMC * NPIX;
    short* T = (which ? Xha : Xll);
    const int c0 = cb * 64, p0 = px * 64;
    const int rrr = t >> 4, pc = (t & 15) * 4;
#pragma unroll
    for (int i = 0; i < 4; ++i) {
      const int c = rrr + 16 * i;
      if (p0 + pc < NPIX) {
        float4 v = *(const float4*)(X + (size_t)(c0 + c) * NPIX + p0 + pc);
        sT[pc + 0][c] = f2bf(v.x); sT[pc + 1][c] = f2bf(v.y);
        sT[pc + 2][c] = f2bf(v.z); sT[pc + 3][c] = f2bf(v.w);
      }
    }
    __syncthreads();
    const int rr = t & 15, qq = (t >> 4) & 3, w = t >> 6;
    const int pxt0 = p0 >> 4, ks0 = c0 >> 5;
#pragma unroll
    for (int i = 0; i < 2; ++i) {
      const int o = w * 2 + i;
      const int pxl = o >> 1, ksl = o & 1;
      if (pxt0 + pxl < 49) {
        short* dst = T + ((size_t)(b * 49 + pxt0 + pxl) * 12 + ks0 + ksl) * 512 + (t & 63) * 8;
        *(bf16x8*)dst = *(const bf16x8*)&sT[pxl * 16 + rr][ksl * 32 + qq * 8];
      }
    }
  } else if (bid < 2784) {        // ---- pack weights (unchanged layouts) ----
    int gid = (bid - 2496) * 256 + t;
    if (gid < 55296) {            // Wf2: ((ct*12+ks)*8+mt)*64+lane
      const int lane = gid & 63;
      const int mt = (gid >> 6) & 7;
      const int ks = (gid >> 9) % 12;
      const int ct = gid / 6144;
      const int chg = ct * 128 + mt * 16 + (lane & 15);    // 0..1151
      const int k = ks * 32 + (lane >> 4) * 8;
      const float* src = (chg < DIMC ? qw + (size_t)chg * DIMC
                                     : kvw + (size_t)(chg - DIMC) * DIMC) + k;
      const float4 a = *(const float4*)src;
      const float4 b = *(const float4*)(src + 4);
      bf16x8 o;
      o[0] = f2bf(a.x); o[1] = f2bf(a.y); o[2] = f2bf(a.z); o[3] = f2bf(a.w);
      o[4] = f2bf(b.x); o[5] = f2bf(b.y); o[6] = f2bf(b.z); o[7] = f2bf(b.w);
      *(bf16x8*)(Wf2 + (size_t)gid * 8) = o;
    } else {                      // Wfp
      const int g2 = gid - 55296;
      const int lane = g2 & 63;
      const int ks = (g2 >> 6) % 12;
      const int mtile = g2 / 768;
      const int row = mtile * 16 + (lane & 15);
      const int k = ks * 32 + (lane >> 4) * 8;
      const float* src = pw + (size_t)row * DIMC + k;
      const float4 a = *(const float4*)src;
      const float4 b = *(const float4*)(src + 4);
      bf16x8 o;
      o[0] = f2bf(a.x); o[1] = f2bf(a.y); o[2] = f2bf(a.z); o[3] = f2bf(a.w);
      o[4] = f2bf(b.x); o[5] = f2bf(b.y); o[6] = f2bf(b.z); o[7] = f2bf(b.w);
      *(bf16x8*)(Wfp + (size_t)g2 * 8) = o;
    }
  } else if (bid < 3176) {        // ---- bias -> Bt3 frag-packed (392 = 8h x 49qt) ----
    const int bb = bid - 2784;
    const int h = bb / 49, qt = bb % 49;
    for (int i = t; i < NPIX; i += 256) sB[i] = biases[h * NPIX + i] * LOG2E;
    __syncthreads();
    const int rr = t & 15, qq = (t >> 4) & 3, w = t >> 6;
    const int qrow = qt * 16 + rr;
    const int i2 = qrow / RES, j2 = qrow - i2 * RES;
    short* dst0 = Bt3 + ((size_t)(h * 49 + qt) * 25) * 512 + (t & 63) * 8;
    const short NEG = f2bf(-1e30f);
    for (int c = w; c < 25; c += 4) {
      short v8[8];
#pragma unroll
      for (int hf = 0; hf < 2; ++hf)
#pragma unroll
        for (int u = 0; u < 4; ++u) {
          const int k = c * 32 + hf * 16 + qq * 4 + u;
          if (k < NPIX) {
            const int i1 = k / RES, j1 = k - i1 * RES;
            int di = i1 - i2; di = di < 0 ? -di : di;
            int dj = j1 - j2; dj = dj < 0 ? -dj : dj;
            v8[hf * 4 + u] = f2bf(sB[di * RES + dj]);
          } else v8[hf * 4 + u] = NEG;      // k>=784: s=-1e30 -> p=0 (uniform tail)
        }
      *(bf16x8*)(dst0 + (size_t)c * 512) = *(const bf16x8*)v8;
    }
  } else {                        // ---- zero fills ----
    const int pp = bid - 3176;
    if (pp < 392) {               // Qb pad d 48-63
      const size_t r = (size_t)pp * 256 + t;
      short* p = Qb + r * DPAD + HDIM;
      *(int4*)p = make_int4(0, 0, 0, 0);
      *(int4*)(p + 8) = make_int4(0, 0, 0, 0);
    } else if (pp < 1192) {       // Kf d 48-63: frags 1,3 lanes 32-63, all chunks
      const int id = (pp - 392) * 256 + t;            // < 204800
      const int l32 = id & 31;
      const int frag = 1 + 2 * ((id >> 5) & 1);
      const int chunk = (id >> 6) % 25;
      const int bh2 = id / 1600;
      short* dst = Kf + (((size_t)bh2 * 25 + chunk) * 4 + frag) * 512 + (32 + l32) * 8;
      *(int4*)dst = make_int4(0, 0, 0, 0);
    } else if (pp < 1256) {       // Kf k 784-799: chunk 24 frags 2,3 all lanes
      const int id = (pp - 1192) * 256 + t;           // < 16384
      const int lane2 = id & 63;
      const int frag = 2 + ((id >> 6) & 1);
      const int bh2 = id >> 7;
      short* dst = Kf + (((size_t)bh2 * 25 + 24) * 4 + frag) * 512 + lane2 * 8;
      *(int4*)dst = make_int4(0, 0, 0, 0);
    } else {                      // Vf k 784-799: chunk 24 frags 0-2 lanes 32-63
      const int id = (pp - 1256) * 256 + t;           // < 12288
      const int bh2 = id / 96;
      const int rem = id - bh2 * 96;
      const int frag = rem >> 5;
      const int l32 = rem & 31;
      short* dst = Vf + (((size_t)bh2 * 25 + 24) * 3 + frag) * 512 + (32 + l32) * 8;
      *(int4*)dst = make_int4(0, 0, 0, 0);
    }
  }
}

// ================= fused QKV GEMM R12: 2 K-steps per LDS buffer, 28 MFMA/barrier ====
// Buffer = 14 frag-rows [ksl 2][pg 7] (14336 B x2 dbuf, fits sM). Wave w stages rows
// {w, w+4, w+8, w+12<14}. 6 iterations, 1 barrier each (was 12). Same math order.
__global__ __launch_bounds__(256) void qkv_tiled(
    const short* __restrict__ Wf2, const float* __restrict__ qb, const float* __restrict__ kvb,
    const short* __restrict__ Xll, const short* __restrict__ Xha,
    short* __restrict__ Qb, short* __restrict__ Kf, short* __restrict__ Vf)
{
  __shared__ __align__(16) short sM[15360];   // [0,14336): B dbuf / V-transpose after loop
  const int t = threadIdx.x;
  const int w = t >> 6, lane = t & 63;
  const int rr = lane & 15, qq = lane >> 4;
  const int ct = blockIdx.x;                  // 0..8
  const int pt = blockIdx.y;                  // 0..111
  const int b = pt / 7, pt7 = pt % 7;
  const int px0 = pt7 * 112;

  const short* Xsel = (ct < 3 ? Xll : Xha);
  const int xt0 = b * 49 + pt7 * 7;

  const short* Ap = Wf2 + (size_t)ct * 12 * 4096 + 2 * w * 512 + lane * 8;

  f32x4 acc[2][7];
#pragma unroll
  for (int mi = 0; mi < 2; ++mi)
#pragma unroll
    for (int pg = 0; pg < 7; ++pg) acc[mi][pg] = (f32x4){0.f, 0.f, 0.f, 0.f};

  // stage 2 ks-slices (s2 -> ks 2*s2, 2*s2+1) into buffer buf; 14 rows = [ksl][pg]
  auto stage2 = [&](int buf, int s2) {
#pragma unroll
    for (int j = 0; j < 4; ++j) {
      const int r = w + 4 * j;
      if (r < 14) {
        const int ksl = r / 7, pg = r - ksl * 7;
        short* l = &sM[buf * 7168 + r * 512];
        const short* g = Xsel + ((size_t)(xt0 + pg) * 12 + 2 * s2 + ksl) * 512 + lane * 8;
        __builtin_amdgcn_global_load_lds((const __attribute__((address_space(1))) void*)g,
                                         (__attribute__((address_space(3))) void*)l, 16, 0, 0);
      }
    }
  };

  stage2(0, 0);
  // A frags for iter 0: [mi][ksl]
  bf16x8 aC[2][2];
  aC[0][0] = *(const bf16x8*)(Ap);
  aC[0][1] = *(const bf16x8*)(Ap + 4096);
  aC[1][0] = *(const bf16x8*)(Ap + 512);
  aC[1][1] = *(const bf16x8*)(Ap + 4096 + 512);
  __syncthreads();                            // drain stage(0)

  for (int s2 = 0; s2 < 6; ++s2) {
    const int buf = s2 & 1;
    if (s2 < 5) stage2(buf ^ 1, s2 + 1);
    const int sn = (s2 < 5 ? s2 + 1 : s2) * 2;
    bf16x8 aN[2][2];
    aN[0][0] = *(const bf16x8*)(Ap + (size_t)sn * 4096);
    aN[0][1] = *(const bf16x8*)(Ap + (size_t)(sn + 1) * 4096);
    aN[1][0] = *(const bf16x8*)(Ap + (size_t)sn * 4096 + 512);
    aN[1][1] = *(const bf16x8*)(Ap + (size_t)(sn + 1) * 4096 + 512);

    const short* sBb = &sM[buf * 7168];
#pragma unroll
    for (int ksl = 0; ksl < 2; ++ksl) {
#pragma unroll
      for (int pg = 0; pg < 7; ++pg) {
        const bf16x8 bf = *(const bf16x8*)(sBb + (ksl * 7 + pg) * 512 + lane * 8);
        acc[0][pg] = __builtin_amdgcn_mfma_f32_16x16x32_bf16(aC[0][ksl], bf, acc[0][pg], 0, 0, 0);
        acc[1][pg] = __builtin_amdgcn_mfma_f32_16x16x32_bf16(aC[1][ksl], bf, acc[1][pg], 0, 0, 0);
      }
    }
    aC[0][0] = aN[0][0]; aC[0][1] = aN[0][1];
    aC[1][0] = aN[1][0]; aC[1][1] = aN[1][1];
    __syncthreads();              // stage(s2+1) landed + all waves done with buf
  }

  if (ct < 3) {
    // ---- Q epilogue: row-major padded Qb, PRE-SCALED by SC2 (R8: bias C-init trick) ----
#pragma unroll
    for (int mi = 0; mi < 2; ++mi) {
      const int ch = ct * 128 + (2 * w + mi) * 16 + qq * 4;
      const float4 bv = *(const float4*)(qb + ch);
      const int hh = ch / HDIM, d0 = ch % HDIM;
#pragma unroll
      for (int pg = 0; pg < 7; ++pg) {
        const int px = px0 + pg * 16 + rr;
        uint2 pk;
        pk.x = pk_rne((acc[mi][pg][0] + bv.x) * SC2, (acc[mi][pg][1] + bv.y) * SC2);
        pk.y = pk_rne((acc[mi][pg][2] + bv.z) * SC2, (acc[mi][pg][3] + bv.w) * SC2);
        *(uint2*)(Qb + (((size_t)b * NHEAD + hh) * NPIX + px) * DPAD + d0) = pk;
      }
    }
  } else if (ct < 6) {
    // ---- K epilogue -> Kf fragment layout ----
#pragma unroll
    for (int mi = 0; mi < 2; ++mi) {
      const int ch = (ct - 3) * 128 + (2 * w + mi) * 16 + qq * 4;
      const float4 bv = *(const float4*)(kvb + ch);
      const int hh = ch / HDIM, dq = ch % HDIM;
      const int fd = dq >> 5;
      const int laneHi = (dq & 31) >> 3;
      const int elo = dq & 7;
#pragma unroll
      for (int pg = 0; pg < 7; ++pg) {
        const int px = px0 + pg * 16 + rr;
        const int chunk = px >> 5, kh = (px >> 4) & 1;
        uint2 pk;
        pk.x = pk_rne(acc[mi][pg][0] + bv.x, acc[mi][pg][1] + bv.y);
        pk.y = pk_rne(acc[mi][pg][2] + bv.z, acc[mi][pg][3] + bv.w);
        short* dst = Kf + ((((size_t)b * NHEAD + hh) * 25 + chunk) * 4 + kh * 2 + fd) * 512
                     + ((px & 15) + (laneHi << 4)) * 8 + elo;
        *(uint2*)dst = pk;
      }
    }
  } else {
    // ---- V epilogue: LDS transpose then Vf fragment stores ----
#pragma unroll
    for (int mi = 0; mi < 2; ++mi) {
      const int chl = (2 * w + mi) * 16 + qq * 4;          // 0..127
      const int chv = (ct - 6) * 128 + chl;                // 0..383
      const float4 bv = *(const float4*)(kvb + DIMC + chv);
      const float bb[4] = {bv.x, bv.y, bv.z, bv.w};
#pragma unroll
      for (int pg = 0; pg < 7; ++pg) {
        const int px = pg * 16 + rr;
#pragma unroll
        for (int j = 0; j < 4; ++j)
          sM[(chl + j) * 120 + px] = f2bf(acc[mi][pg][j] + bb[j]);
      }
    }
    __syncthreads();
    for (int id = t; id < 1792; id += 256) {
      const int r = id / 14, o = id - r * 14;
      const int k = px0 + o * 8;
      const int chunk = k >> 5, qv = (k >> 3) & 3;
      const int chv = (ct - 6) * 128 + r;
      const int hh = chv / HDIM, d = chv % HDIM;
      short* dst = Vf + ((((size_t)b * NHEAD + hh) * 25 + chunk) * 3 + (d >> 4)) * 512
                   + ((d & 15) + (qv << 4)) * 8;
      *(bf16x8*)dst = *(const bf16x8*)&sM[r * 120 + o * 8];
    }
  }
}

// ================= attention (R8-exact): bias C-init QK, cvt_pk pack, sp via ones-MFMA ====
struct Chain { float sp; f32x4 O0, O1, O2; };

__device__ __forceinline__ void store_p(
    const f32x4 d0, const f32x4 d1, short* sPt, const int rr, const int qq)
{
  const float p0 = exp2f(d0[0]), p1 = exp2f(d0[1]), p2 = exp2f(d0[2]), p3 = exp2f(d0[3]);
  const float p4 = exp2f(d1[0]), p5 = exp2f(d1[1]), p6 = exp2f(d1[2]), p7 = exp2f(d1[3]);
  uint2 w0; w0.x = cvtpk(p0, p1); w0.y = cvtpk(p2, p3);
  uint2 w1; w1.x = cvtpk(p4, p5); w1.y = cvtpk(p6, p7);
  *(uint2*)(sPt + rr * 40 + qq * 4) = w0;
  *(uint2*)(sPt + rr * 40 + 16 + qq * 4) = w1;
}

__global__ __launch_bounds__(256) void attn_kernel(
    const short* __restrict__ Q, const short* __restrict__ Kf,
    const short* __restrict__ Vf, const short* __restrict__ Bt3,
    short* __restrict__ AOf)
{
  // LDS union: [0,10240) sP[w][chain][16*40] shorts; [0,19968) merge f32 [13][384].
  __shared__ __align__(16) char sMem[20480];
  short* sPbase = (short*)sMem;
  const int t = threadIdx.x;
  const int w = t >> 6, lane = t & 63;
  const int rr = lane & 15, qq = lane >> 4;
  const int x = blockIdx.x;            // 3200 = 8 * 400
  const int h = x & 7;                 // XCD pin: one head per XCD
  const int i = x >> 3;                // 0..399 = b*25 + qt
  const int b = i / 25, qt = i - b * 25;
  const int qA = qt * 32;
  const bool hasB = (qA + 16 < NPIX);
  const int bh = b * NHEAD + h;

  const short* QpA = Q + ((size_t)bh * NPIX + qA + rr) * DPAD + qq * 8;
  const short* QpB = Q + ((size_t)bh * NPIX + (hasB ? qA + 16 : qA) + rr) * DPAD + qq * 8;
  const bf16x8 qfA0 = *(const bf16x8*)QpA;
  const bf16x8 qfA1 = *(const bf16x8*)(QpA + 32);
  const bf16x8 qfB0 = *(const bf16x8*)QpB;
  const bf16x8 qfB1 = *(const bf16x8*)(QpB + 32);

  const short* Kfp = Kf + (size_t)bh * (25 * 4 * 512) + lane * 8;
  const short* Vfp = Vf + (size_t)bh * (25 * 3 * 512) + lane * 8;
  const short* BpA = Bt3 + ((size_t)(h * 49 + 2 * qt) * 25) * 512 + lane * 8;
  const short* BpB = Bt3 + ((size_t)(h * 49 + (hasB ? 2 * qt + 1 : 2 * qt)) * 25) * 512 + lane * 8;
  short* sPA = sPbase + (w * 2 + 0) * 640;
  short* sPB = sPbase + (w * 2 + 1) * 640;

  const bf16x8 onesf = {(short)0x3F80, (short)0x3F80, (short)0x3F80, (short)0x3F80,
                        (short)0x3F80, (short)0x3F80, (short)0x3F80, (short)0x3F80};

  Chain cA, cB;
  cA.O0 = (f32x4){0.f,0.f,0.f,0.f}; cA.O1 = cA.O0; cA.O2 = cA.O0;
  cB.O0 = cA.O0; cB.O1 = cA.O0; cB.O2 = cA.O0;
  f32x4 spA = cA.O0, spB = cA.O0;

  const int cbeg = w * 6;
  const int cend = (w == 3) ? 25 : cbeg + 6;   // wave k-split: 6/6/6/7 chunks

  for (int c = cbeg; c < cend; ++c) {
    const uint4 bA = *(const uint4*)(BpA + (size_t)c * 512);
    const uint4 bB = *(const uint4*)(BpB + (size_t)c * 512);
    const short* kc = Kfp + (size_t)c * 2048;
    const bf16x8 ka0 = *(const bf16x8*)kc;
    const bf16x8 ka1 = *(const bf16x8*)(kc + 512);
    const bf16x8 kb0 = *(const bf16x8*)(kc + 1024);
    const bf16x8 kb1 = *(const bf16x8*)(kc + 1536);

    // bias as C-init (Bt3 layout == C-fragment layout), f32-exact
    f32x4 dA0 = (f32x4){blo(bA.x), bhi(bA.x), blo(bA.y), bhi(bA.y)};
    f32x4 dA1 = (f32x4){blo(bA.z), bhi(bA.z), blo(bA.w), bhi(bA.w)};
    f32x4 dB0 = (f32x4){blo(bB.x), bhi(bB.x), blo(bB.y), bhi(bB.y)};
    f32x4 dB1 = (f32x4){blo(bB.z), bhi(bB.z), blo(bB.w), bhi(bB.w)};

    __builtin_amdgcn_s_setprio(1);
    dA0 = __builtin_amdgcn_mfma_f32_16x16x32_bf16(ka0, qfA0, dA0, 0, 0, 0);
    dA0 = __builtin_amdgcn_mfma_f32_16x16x32_bf16(ka1, qfA1, dA0, 0, 0, 0);
    dB0 = __builtin_amdgcn_mfma_f32_16x16x32_bf16(ka0, qfB0, dB0, 0, 0, 0);
    dB0 = __builtin_amdgcn_mfma_f32_16x16x32_bf16(ka1, qfB1, dB0, 0, 0, 0);
    dA1 = __builtin_amdgcn_mfma_f32_16x16x32_bf16(kb0, qfA0, dA1, 0, 0, 0);
    dA1 = __builtin_amdgcn_mfma_f32_16x16x32_bf16(kb1, qfA1, dA1, 0, 0, 0);
    dB1 = __builtin_amdgcn_mfma_f32_16x16x32_bf16(kb0, qfB0, dB1, 0, 0, 0);
    dB1 = __builtin_amdgcn_mfma_f32_16x16x32_bf16(kb1, qfB1, dB1, 0, 0, 0);
    __builtin_amdgcn_s_setprio(0);

    store_p(dA0, dA1, sPA, rr, qq);
    store_p(dB0, dB1, sPB, rr, qq);

    const short* vc = Vfp + (size_t)c * 1536;
    const bf16x8 vf0 = *(const bf16x8*)vc;
    const bf16x8 vf1 = *(const bf16x8*)(vc + 512);
    const bf16x8 vf2 = *(const bf16x8*)(vc + 1024);
    const bf16x8 pfA = *(const bf16x8*)(sPA + rr * 40 + qq * 8);
    const bf16x8 pfB = *(const bf16x8*)(sPB + rr * 40 + qq * 8);
    __builtin_amdgcn_s_setprio(1);
    cA.O0 = __builtin_amdgcn_mfma_f32_16x16x32_bf16(vf0, pfA, cA.O0, 0, 0, 0);
    cA.O1 = __builtin_amdgcn_mfma_f32_16x16x32_bf16(vf1, pfA, cA.O1, 0, 0, 0);
    cA.O2 = __builtin_amdgcn_mfma_f32_16x16x32_bf16(vf2, pfA, cA.O2, 0, 0, 0);
    spA   = __builtin_amdgcn_mfma_f32_16x16x32_bf16(onesf, pfA, spA, 0, 0, 0);
    cB.O0 = __builtin_amdgcn_mfma_f32_16x16x32_bf16(vf0, pfB, cB.O0, 0, 0, 0);
    cB.O1 = __builtin_amdgcn_mfma_f32_16x16x32_bf16(vf1, pfB, cB.O1, 0, 0, 0);
    cB.O2 = __builtin_amdgcn_mfma_f32_16x16x32_bf16(vf2, pfB, cB.O2, 0, 0, 0);
    spB   = __builtin_amdgcn_mfma_f32_16x16x32_bf16(onesf, pfB, spB, 0, 0, 0);
    __builtin_amdgcn_s_setprio(0);
  }
  cA.sp = spA[0];                      // every row of ones-MFMA D = full k-sum for q=lane&15
  cB.sp = spB[0];

  // ---- cross-wave merge: plain lane-wise sums (no max -> no rescale) ----
  __syncthreads();
  float* mbuf = (float*)sMem;          // [j:13][wc:6][lane:64]
  if (w > 0) {
    const int col = ((w - 1) * 2 + 0) * 64 + lane;
    const int colB = col + 64;
    float vals[13] = {cA.O0[0], cA.O0[1], cA.O0[2], cA.O0[3],
                      cA.O1[0], cA.O1[1], cA.O1[2], cA.O1[3],
                      cA.O2[0], cA.O2[1], cA.O2[2], cA.O2[3], cA.sp};
    float valsB[13] = {cB.O0[0], cB.O0[1], cB.O0[2], cB.O0[3],
                       cB.O1[0], cB.O1[1], cB.O1[2], cB.O1[3],
                       cB.O2[0], cB.O2[1], cB.O2[2], cB.O2[3], cB.sp};
#pragma unroll
    for (int j = 0; j < 13; ++j) mbuf[j * 384 + col] = vals[j];
#pragma unroll
    for (int j = 0; j < 13; ++j) mbuf[j * 384 + colB] = valsB[j];
  }
  __syncthreads();
  if (w != 0) return;

#pragma unroll
  for (int ww = 0; ww < 3; ++ww) {
    const int col = (ww * 2 + 0) * 64 + lane;
    const int colB = col + 64;
#pragma unroll
    for (int j = 0; j < 4; ++j) {
      cA.O0[j] += mbuf[j * 384 + col];
      cA.O1[j] += mbuf[(4 + j) * 384 + col];
      cA.O2[j] += mbuf[(8 + j) * 384 + col];
      cB.O0[j] += mbuf[j * 384 + colB];
      cB.O1[j] += mbuf[(4 + j) * 384 + colB];
      cB.O2[j] += mbuf[(8 + j) * 384 + colB];
    }
    cA.sp += mbuf[12 * 384 + col];
    cB.sp += mbuf[12 * 384 + colB];
  }

  {
    const float invA = 1.f / cA.sp;    // sp already q-complete per lane (ones-MFMA)
    const f32x4 OA[3] = {cA.O0, cA.O1, cA.O2};
    short* base = AOf + ((size_t)(b * 49 + 2 * qt) * 12) * 512;
#pragma unroll
    for (int part = 0; part < 3; ++part) {
      const int ch = h * HDIM + part * 16 + qq * 4;
      uint2 pk;
      pk.x = pk_rne(OA[part][0] * invA, OA[part][1] * invA);
      pk.y = pk_rne(OA[part][2] * invA, OA[part][3] * invA);
      short* dst = base + (ch >> 5) * 512 + (rr + (((ch >> 3) & 3) << 4)) * 8 + (ch & 7);
      *(uint2*)dst = pk;
    }
  }
  if (hasB) {
    const float invB = 1.f / cB.sp;
    const f32x4 OB[3] = {cB.O0, cB.O1, cB.O2};
    short* base = AOf + ((size_t)(b * 49 + 2 * qt + 1) * 12) * 512;
#pragma unroll
    for (int part = 0; part < 3; ++part) {
      const int ch = h * HDIM + part * 16 + qq * 4;
      uint2 pk;
      pk.x = pk_rne(OB[part][0] * invB, OB[part][1] * invB);
      pk.y = pk_rne(OB[part][2] * invB, OB[part][3] * invB);
      short* dst = base + (ch >> 5) * 512 + (rr + (((ch >> 3) & 3) << 4)) * 8 + (ch & 7);
      *(uint2*)dst = pk;
    }
  }
}

// ================= proj GEMM (R9 shape: 2 mtiles x 7 pg = 14 accs, frag loads) ==========
__global__ __launch_bounds__(128) void proj_gemm(
    const short* __restrict__ Wfp, const float* __restrict__ pb,
    const short* __restrict__ AOf, float* __restrict__ out)
{
  const int t = threadIdx.x;
  const int w = t >> 6, lane = t & 63;     // w in {0,1}
  const int rr = lane & 15, qq = lane >> 4;
  const int ct = blockIdx.x;               // 0..5 : 64-ch tile
  const int pt = blockIdx.y;               // 0..111
  const int b = pt / 7, pt7 = pt % 7;
  const int px0 = pt7 * 112;

  const short* Ap0 = Wfp + ((size_t)(ct * 4 + 2 * w) * 12) * 512 + lane * 8;
  const short* Ap1 = Ap0 + 12 * 512;
  const short* Xp[7];
#pragma unroll
  for (int pg = 0; pg < 7; ++pg)
    Xp[pg] = AOf + ((size_t)(b * 49 + pt7 * 7 + pg) * 12) * 512 + lane * 8;

  f32x4 acc[2][7];
#pragma unroll
  for (int mi = 0; mi < 2; ++mi)
#pragma unroll
    for (int pg = 0; pg < 7; ++pg) acc[mi][pg] = (f32x4){0.f, 0.f, 0.f, 0.f};

  bf16x8 a0c = *(const bf16x8*)(Ap0);
  bf16x8 a1c = *(const bf16x8*)(Ap1);
  bf16x8 bcur[7];
#pragma unroll
  for (int pg = 0; pg < 7; ++pg) bcur[pg] = *(const bf16x8*)(Xp[pg]);

#pragma unroll 2
  for (int s = 0; s < 12; ++s) {
    const int sn = s + (s < 11 ? 1 : 0);
    const bf16x8 a0n = *(const bf16x8*)(Ap0 + (size_t)sn * 512);
    const bf16x8 a1n = *(const bf16x8*)(Ap1 + (size_t)sn * 512);
    bf16x8 bnxt[7];
#pragma unroll
    for (int pg = 0; pg < 7; ++pg) bnxt[pg] = *(const bf16x8*)(Xp[pg] + (size_t)sn * 512);

#pragma unroll
    for (int pg = 0; pg < 7; ++pg) {
      acc[0][pg] = __builtin_amdgcn_mfma_f32_16x16x32_bf16(a0c, bcur[pg], acc[0][pg], 0, 0, 0);
      acc[1][pg] = __builtin_amdgcn_mfma_f32_16x16x32_bf16(a1c, bcur[pg], acc[1][pg], 0, 0, 0);
    }
    a0c = a0n; a1c = a1n;
#pragma unroll
    for (int pg = 0; pg < 7; ++pg) bcur[pg] = bnxt[pg];
  }

#pragma unroll
  for (int mi = 0; mi < 2; ++mi) {
    const int ch0 = ct * 64 + (2 * w + mi) * 16 + qq * 4;
    const float4 bv = *(const float4*)(pb + ch0);
#pragma unroll
    for (int pg = 0; pg < 7; ++pg) {
      const int px = px0 + pg * 16 + rr;
      float* o = out + ((size_t)b * DIMC + ch0) * NPIX + px;
      o[0] = acc[mi][pg][0] + bv.x;
      o[NPIX] = acc[mi][pg][1] + bv.y;
      o[2 * NPIX] = acc[mi][pg][2] + bv.z;
      o[3 * NPIX] = acc[mi][pg][3] + bv.w;
    }
  }
}

extern "C" void kernel_launch(void* const* d_in, const int* in_sizes, int n_in,
                              void* d_out, int out_size, void* d_ws, size_t ws_size,
                              hipStream_t stream)
{
  const float* ll     = (const float*)d_in[0];
  const float* ha     = (const float*)d_in[1];
  const float* q_w    = (const float*)d_in[2];
  const float* q_b    = (const float*)d_in[3];
  const float* kv_w   = (const float*)d_in[4];
  const float* kv_b   = (const float*)d_in[5];
  const float* proj_w = (const float*)d_in[6];
  const float* proj_b = (const float*)d_in[7];
  const float* biases = (const float*)d_in[8];
  // d_in[9] (bias_idxs) unused: index == |i1-i2|*28+|j1-j2| (validated R1/R2)
  float* out = (float*)d_out;

  short* Qb  = (short*)d_ws;                          // 16*8*784*64   = 6,422,528
  short* Kf  = Qb  + (size_t)NB * NHEAD * NPIX * DPAD;
  short* Vf  = Kf  + (size_t)128 * 25 * 4 * 512;      //               = 6,553,600
  short* Xll = Vf  + (size_t)128 * 25 * 3 * 512;      //               = 4,915,200
  short* Xha = Xll + (size_t)NB * 49 * 12 * 512;      //               = 4,816,896
  short* AOf = Xha + (size_t)NB * 49 * 12 * 512;
  short* Bt3 = AOf + (size_t)NB * 49 * 12 * 512;
  short* Wf2 = Bt3 + (size_t)NHEAD * 49 * 25 * 512;   //               = 5,017,600
  short* Wfp = Wf2 + (size_t)55296 * 8;

  prep_kernel<<<dim3(4480), 256, 0, stream>>>(ll, ha, q_w, kv_w, proj_w, biases,
                                              Xll, Xha, Wf2, Wfp, Bt3, Qb, Kf, Vf);
  qkv_tiled<<<dim3(9, 112), 256, 0, stream>>>(Wf2, q_b, kv_b, Xll, Xha, Qb, Kf, Vf);
  attn_kernel<<<dim3(3200), 256, 0, stream>>>(Qb, Kf, Vf, Bt3, AOf);
  proj_gemm<<<dim3(6, 112), 128, 0, stream>>>(Wfp, proj_b, AOf, out);
}

// Round 14
// 188.802 us; speedup vs baseline: 1.0371x; 1.0371x over previous
//
#include <hip/hip_runtime.h>

#define RES    28
#define DIMC   384
#define NHEAD  8
#define HDIM   48
#define DPAD   64
#define NPIX   784
#define NB     16
#define SC2    0.20823294f    // 48^-0.5 * log2(e)
#define LOG2E  1.44269504f

typedef short bf16x8 __attribute__((ext_vector_type(8)));
typedef float f32x4  __attribute__((ext_vector_type(4)));

__device__ __forceinline__ short f2bf(float x) {
  union { float f; unsigned u; } v; v.f = x;
  return (short)((v.u + 0x7FFFu + ((v.u >> 16) & 1u)) >> 16);   // RNE
}
__device__ __forceinline__ unsigned pk_rne(float a, float b) {
  union { float f; unsigned u; } x, y; x.f = a; y.f = b;
  return __builtin_amdgcn_perm(y.u + 0x7FFFu + ((y.u >> 16) & 1u),
                               x.u + 0x7FFFu + ((x.u >> 16) & 1u), 0x07060302u);
}
__device__ __forceinline__ unsigned cvtpk(float a, float b) {   // lo=bf16(a), hi=bf16(b), RNE
  unsigned r;
  asm("v_cvt_pk_bf16_f32 %0, %1, %2" : "=v"(r) : "v"(a), "v"(b));
  return r;
}
__device__ __forceinline__ float blo(unsigned u) { union { unsigned u; float f; } v; v.u = u << 16; return v.f; }
__device__ __forceinline__ float bhi(unsigned u) { union { unsigned u; float f; } v; v.u = u & 0xFFFF0000u; return v.f; }

// ======================= FRAGMENT-PACKED LAYOUTS (R6) =======================
// Xf [b][pxt 49][ks 12][lane][8] : X[b][px=pxt*16+(l&15)][ch=ks*32+(l>>4)*8+e]
// Kf [bh][chunk 25][frag 4][lane][8] : frag=kh*2+dh ->
//      K[bh][k=chunk*32+kh*16+(l&15)][d=dh*32+(l>>4)*8+e]  (d48-63, k784-799 zero)
// Vf [bh][chunk 25][frag 3][lane][8] : V[bh][d=frag*16+(l&15)][k=chunk*32+(l>>4)*8+e]
// Bt3[h][qt 49][chunk 25][lane][8] : shorts 0-3 = bias[q=qt*16+(l&15)][k=c*32+qq*4+u],
//      shorts 4-7 = k+16; k>=784 slots hold bf16(-1e30) -> p = 0 (uniform tail).
//      R8: this IS the QK C-fragment layout (col=lane&15=q, row=qq*4+reg) -> C-init.
// AOf[b][pxt 49][ks 12][lane][8] : attn output (proj reads it)
// Qb row-major (b,h,784,64) padded; R8: Q pre-scaled by SC2 at qkv epilogue.
// R14 = resubmit of R11-best (193.3us measured); R13 bench was an infra failure.

// ================= prep: transpose->Xf, pack W, bias->Bt3, zeros ==========
__global__ __launch_bounds__(256) void prep_kernel(
    const float* __restrict__ ll, const float* __restrict__ ha,
    const float* __restrict__ qw, const float* __restrict__ kvw, const float* __restrict__ pw,
    const float* __restrict__ biases,
    short* __restrict__ Xll, short* __restrict__ Xha,
    short* __restrict__ Wf2, short* __restrict__ Wfp,
    short* __restrict__ Bt3, short* __restrict__ Qb,
    short* __restrict__ Kf, short* __restrict__ Vf)
{
  __shared__ __align__(16) short sT[64][72];
  __shared__ float sB[NPIX];
  const int bid = blockIdx.x, t = threadIdx.x;

  if (bid < 2496) {               // ---- transpose (b,c,pix) f32 -> Xf frag layout ----
    const int px = bid % 13, cb = (bid / 13) % 6, zz = bid / 78;
    const int which = zz >> 4, b = zz & 15;
    const float* X = (which ? ha : ll) + (size_t)b * DIMC * NPIX;
    short* T = (which ? Xha : Xll);
    const int c0 = cb * 64, p0 = px * 64;
    const int rrr = t >> 4, pc = (t & 15) * 4;
#pragma unroll
    for (int i = 0; i < 4; ++i) {
      const int c = rrr + 16 * i;
      if (p0 + pc < NPIX) {
        float4 v = *(const float4*)(X + (size_t)(c0 + c) * NPIX + p0 + pc);
        sT[pc + 0][c] = f2bf(v.x); sT[pc + 1][c] = f2bf(v.y);
        sT[pc + 2][c] = f2bf(v.z); sT[pc + 3][c] = f2bf(v.w);
      }
    }
    __syncthreads();
    const int rr = t & 15, qq = (t >> 4) & 3, w = t >> 6;
    const int pxt0 = p0 >> 4, ks0 = c0 >> 5;
#pragma unroll
    for (int i = 0; i < 2; ++i) {
      const int o = w * 2 + i;
      const int pxl = o >> 1, ksl = o & 1;
      if (pxt0 + pxl < 49) {
        short* dst = T + ((size_t)(b * 49 + pxt0 + pxl) * 12 + ks0 + ksl) * 512 + (t & 63) * 8;
        *(bf16x8*)dst = *(const bf16x8*)&sT[pxl * 16 + rr][ksl * 32 + qq * 8];
      }
    }
  } else if (bid < 2784) {        // ---- pack weights (unchanged layouts) ----
    int gid = (bid - 2496) * 256 + t;
    if (gid < 55296) {            // Wf2: ((ct*12+ks)*8+mt)*64+lane
      const int lane = gid & 63;
      const int mt = (gid >> 6) & 7;
      const int ks = (gid >> 9) % 12;
      const int ct = gid / 6144;
      const int chg = ct * 128 + mt * 16 + (lane & 15);    // 0..1151
      const int k = ks * 32 + (lane >> 4) * 8;
      const float* src = (chg < DIMC ? qw + (size_t)chg * DIMC
                                     : kvw + (size_t)(chg - DIMC) * DIMC) + k;
      const float4 a = *(const float4*)src;
      const float4 b = *(const float4*)(src + 4);
      bf16x8 o;
      o[0] = f2bf(a.x); o[1] = f2bf(a.y); o[2] = f2bf(a.z); o[3] = f2bf(a.w);
      o[4] = f2bf(b.x); o[5] = f2bf(b.y); o[6] = f2bf(b.z); o[7] = f2bf(b.w);
      *(bf16x8*)(Wf2 + (size_t)gid * 8) = o;
    } else {                      // Wfp
      const int g2 = gid - 55296;
      const int lane = g2 & 63;
      const int ks = (g2 >> 6) % 12;
      const int mtile = g2 / 768;
      const int row = mtile * 16 + (lane & 15);
      const int k = ks * 32 + (lane >> 4) * 8;
      const float* src = pw + (size_t)row * DIMC + k;
      const float4 a = *(const float4*)src;
      const float4 b = *(const float4*)(src + 4);
      bf16x8 o;
      o[0] = f2bf(a.x); o[1] = f2bf(a.y); o[2] = f2bf(a.z); o[3] = f2bf(a.w);
      o[4] = f2bf(b.x); o[5] = f2bf(b.y); o[6] = f2bf(b.z); o[7] = f2bf(b.w);
      *(bf16x8*)(Wfp + (size_t)g2 * 8) = o;
    }
  } else if (bid < 3176) {        // ---- bias -> Bt3 frag-packed (392 = 8h x 49qt) ----
    const int bb = bid - 2784;
    const int h = bb / 49, qt = bb % 49;
    for (int i = t; i < NPIX; i += 256) sB[i] = biases[h * NPIX + i] * LOG2E;
    __syncthreads();
    const int rr = t & 15, qq = (t >> 4) & 3, w = t >> 6;
    const int qrow = qt * 16 + rr;
    const int i2 = qrow / RES, j2 = qrow - i2 * RES;
    short* dst0 = Bt3 + ((size_t)(h * 49 + qt) * 25) * 512 + (t & 63) * 8;
    const short NEG = f2bf(-1e30f);
    for (int c = w; c < 25; c += 4) {
      short v8[8];
#pragma unroll
      for (int hf = 0; hf < 2; ++hf)
#pragma unroll
        for (int u = 0; u < 4; ++u) {
          const int k = c * 32 + hf * 16 + qq * 4 + u;
          if (k < NPIX) {
            const int i1 = k / RES, j1 = k - i1 * RES;
            int di = i1 - i2; di = di < 0 ? -di : di;
            int dj = j1 - j2; dj = dj < 0 ? -dj : dj;
            v8[hf * 4 + u] = f2bf(sB[di * RES + dj]);
          } else v8[hf * 4 + u] = NEG;      // k>=784: s=-1e30 -> p=0 (uniform tail)
        }
      *(bf16x8*)(dst0 + (size_t)c * 512) = *(const bf16x8*)v8;
    }
  } else {                        // ---- zero fills ----
    const int pp = bid - 3176;
    if (pp < 392) {               // Qb pad d 48-63
      const size_t r = (size_t)pp * 256 + t;
      short* p = Qb + r * DPAD + HDIM;
      *(int4*)p = make_int4(0, 0, 0, 0);
      *(int4*)(p + 8) = make_int4(0, 0, 0, 0);
    } else if (pp < 1192) {       // Kf d 48-63: frags 1,3 lanes 32-63, all chunks
      const int id = (pp - 392) * 256 + t;            // < 204800
      const int l32 = id & 31;
      const int frag = 1 + 2 * ((id >> 5) & 1);
      const int chunk = (id >> 6) % 25;
      const int bh2 = id / 1600;
      short* dst = Kf + (((size_t)bh2 * 25 + chunk) * 4 + frag) * 512 + (32 + l32) * 8;
      *(int4*)dst = make_int4(0, 0, 0, 0);
    } else if (pp < 1256) {       // Kf k 784-799: chunk 24 frags 2,3 all lanes
      const int id = (pp - 1192) * 256 + t;           // < 16384
      const int lane2 = id & 63;
      const int frag = 2 + ((id >> 6) & 1);
      const int bh2 = id >> 7;
      short* dst = Kf + (((size_t)bh2 * 25 + 24) * 4 + frag) * 512 + lane2 * 8;
      *(int4*)dst = make_int4(0, 0, 0, 0);
    } else {                      // Vf k 784-799: chunk 24 frags 0-2 lanes 32-63
      const int id = (pp - 1256) * 256 + t;           // < 12288
      const int bh2 = id / 96;
      const int rem = id - bh2 * 96;
      const int frag = rem >> 5;
      const int l32 = rem & 31;
      short* dst = Vf + (((size_t)bh2 * 25 + 24) * 3 + frag) * 512 + (32 + l32) * 8;
      *(int4*)dst = make_int4(0, 0, 0, 0);
    }
  }
}

// ================= fused QKV GEMM: LDS-staged shared B (R7), Q pre-scaled by SC2 (R8) ====
__global__ __launch_bounds__(256) void qkv_tiled(
    const short* __restrict__ Wf2, const float* __restrict__ qb, const float* __restrict__ kvb,
    const short* __restrict__ Xll, const short* __restrict__ Xha,
    short* __restrict__ Qb, short* __restrict__ Kf, short* __restrict__ Vf)
{
  __shared__ __align__(16) short sM[15360];   // [0,7168): B dbuf / V-transpose after loop
  const int t = threadIdx.x;
  const int w = t >> 6, lane = t & 63;
  const int rr = lane & 15, qq = lane >> 4;
  const int ct = blockIdx.x;                  // 0..8
  const int pt = blockIdx.y;                  // 0..111
  const int b = pt / 7, pt7 = pt % 7;
  const int px0 = pt7 * 112;

  const short* Xsel = (ct < 3 ? Xll : Xha);
  const int xt0 = b * 49 + pt7 * 7;

  const short* Ap = Wf2 + (size_t)ct * 12 * 4096 + 2 * w * 512 + lane * 8;

  f32x4 acc[2][7];
#pragma unroll
  for (int mi = 0; mi < 2; ++mi)
#pragma unroll
    for (int pg = 0; pg < 7; ++pg) acc[mi][pg] = (f32x4){0.f, 0.f, 0.f, 0.f};

  auto stageB = [&](int buf, int s) {
    short* l0 = &sM[buf * 3584 + w * 512];
    const short* g0 = Xsel + ((size_t)(xt0 + w) * 12 + s) * 512 + lane * 8;
    __builtin_amdgcn_global_load_lds((const __attribute__((address_space(1))) void*)g0,
                                     (__attribute__((address_space(3))) void*)l0, 16, 0, 0);
    if (w < 3) {
      short* l1 = &sM[buf * 3584 + (w + 4) * 512];
      const short* g1 = Xsel + ((size_t)(xt0 + w + 4) * 12 + s) * 512 + lane * 8;
      __builtin_amdgcn_global_load_lds((const __attribute__((address_space(1))) void*)g1,
                                       (__attribute__((address_space(3))) void*)l1, 16, 0, 0);
    }
  };

  stageB(0, 0);
  bf16x8 a0c = *(const bf16x8*)(Ap);
  bf16x8 a1c = *(const bf16x8*)(Ap + 512);
  __syncthreads();                            // drain stage(0)

  for (int s = 0; s < 12; ++s) {
    const int buf = s & 1;
    if (s < 11) stageB(buf ^ 1, s + 1);
    const int sn = s < 11 ? s + 1 : s;
    const short* an = Ap + (size_t)sn * 4096;
    const bf16x8 a0n = *(const bf16x8*)(an);
    const bf16x8 a1n = *(const bf16x8*)(an + 512);

    const short* sBb = &sM[buf * 3584];
#pragma unroll
    for (int pg = 0; pg < 7; ++pg) {
      const bf16x8 bf = *(const bf16x8*)(sBb + pg * 512 + lane * 8);
      acc[0][pg] = __builtin_amdgcn_mfma_f32_16x16x32_bf16(a0c, bf, acc[0][pg], 0, 0, 0);
      acc[1][pg] = __builtin_amdgcn_mfma_f32_16x16x32_bf16(a1c, bf, acc[1][pg], 0, 0, 0);
    }
    a0c = a0n; a1c = a1n;
    __syncthreads();
  }

  if (ct < 3) {
    // ---- Q epilogue: row-major padded Qb, PRE-SCALED by SC2 (R8: bias C-init trick) ----
#pragma unroll
    for (int mi = 0; mi < 2; ++mi) {
      const int ch = ct * 128 + (2 * w + mi) * 16 + qq * 4;
      const float4 bv = *(const float4*)(qb + ch);
      const int hh = ch / HDIM, d0 = ch % HDIM;
#pragma unroll
      for (int pg = 0; pg < 7; ++pg) {
        const int px = px0 + pg * 16 + rr;
        uint2 pk;
        pk.x = pk_rne((acc[mi][pg][0] + bv.x) * SC2, (acc[mi][pg][1] + bv.y) * SC2);
        pk.y = pk_rne((acc[mi][pg][2] + bv.z) * SC2, (acc[mi][pg][3] + bv.w) * SC2);
        *(uint2*)(Qb + (((size_t)b * NHEAD + hh) * NPIX + px) * DPAD + d0) = pk;
      }
    }
  } else if (ct < 6) {
    // ---- K epilogue -> Kf fragment layout ----
#pragma unroll
    for (int mi = 0; mi < 2; ++mi) {
      const int ch = (ct - 3) * 128 + (2 * w + mi) * 16 + qq * 4;
      const float4 bv = *(const float4*)(kvb + ch);
      const int hh = ch / HDIM, dq = ch % HDIM;
      const int fd = dq >> 5;
      const int laneHi = (dq & 31) >> 3;
      const int elo = dq & 7;
#pragma unroll
      for (int pg = 0; pg < 7; ++pg) {
        const int px = px0 + pg * 16 + rr;
        const int chunk = px >> 5, kh = (px >> 4) & 1;
        uint2 pk;
        pk.x = pk_rne(acc[mi][pg][0] + bv.x, acc[mi][pg][1] + bv.y);
        pk.y = pk_rne(acc[mi][pg][2] + bv.z, acc[mi][pg][3] + bv.w);
        short* dst = Kf + ((((size_t)b * NHEAD + hh) * 25 + chunk) * 4 + kh * 2 + fd) * 512
                     + ((px & 15) + (laneHi << 4)) * 8 + elo;
        *(uint2*)dst = pk;
      }
    }
  } else {
    // ---- V epilogue: LDS transpose then Vf fragment stores ----
#pragma unroll
    for (int mi = 0; mi < 2; ++mi) {
      const int chl = (2 * w + mi) * 16 + qq * 4;          // 0..127
      const int chv = (ct - 6) * 128 + chl;                // 0..383
      const float4 bv = *(const float4*)(kvb + DIMC + chv);
      const float bb[4] = {bv.x, bv.y, bv.z, bv.w};
#pragma unroll
      for (int pg = 0; pg < 7; ++pg) {
        const int px = pg * 16 + rr;
#pragma unroll
        for (int j = 0; j < 4; ++j)
          sM[(chl + j) * 120 + px] = f2bf(acc[mi][pg][j] + bb[j]);
      }
    }
    __syncthreads();
    for (int id = t; id < 1792; id += 256) {
      const int r = id / 14, o = id - r * 14;
      const int k = px0 + o * 8;
      const int chunk = k >> 5, qv = (k >> 3) & 3;
      const int chv = (ct - 6) * 128 + r;
      const int hh = chv / HDIM, d = chv % HDIM;
      short* dst = Vf + ((((size_t)b * NHEAD + hh) * 25 + chunk) * 3 + (d >> 4)) * 512
                   + ((d & 15) + (qv << 4)) * 8;
      *(bf16x8*)dst = *(const bf16x8*)&sM[r * 120 + o * 8];
    }
  }
}

// ================= attention (R8-exact): bias C-init QK, cvt_pk pack, sp via ones-MFMA ====
struct Chain { float sp; f32x4 O0, O1, O2; };

__device__ __forceinline__ void store_p(
    const f32x4 d0, const f32x4 d1, short* sPt, const int rr, const int qq)
{
  const float p0 = exp2f(d0[0]), p1 = exp2f(d0[1]), p2 = exp2f(d0[2]), p3 = exp2f(d0[3]);
  const float p4 = exp2f(d1[0]), p5 = exp2f(d1[1]), p6 = exp2f(d1[2]), p7 = exp2f(d1[3]);
  uint2 w0; w0.x = cvtpk(p0, p1); w0.y = cvtpk(p2, p3);
  uint2 w1; w1.x = cvtpk(p4, p5); w1.y = cvtpk(p6, p7);
  *(uint2*)(sPt + rr * 40 + qq * 4) = w0;
  *(uint2*)(sPt + rr * 40 + 16 + qq * 4) = w1;
}

__global__ __launch_bounds__(256) void attn_kernel(
    const short* __restrict__ Q, const short* __restrict__ Kf,
    const short* __restrict__ Vf, const short* __restrict__ Bt3,
    short* __restrict__ AOf)
{
  // LDS union: [0,10240) sP[w][chain][16*40] shorts; [0,19968) merge f32 [13][384].
  __shared__ __align__(16) char sMem[20480];
  short* sPbase = (short*)sMem;
  const int t = threadIdx.x;
  const int w = t >> 6, lane = t & 63;
  const int rr = lane & 15, qq = lane >> 4;
  const int x = blockIdx.x;            // 3200 = 8 * 400
  const int h = x & 7;                 // XCD pin: one head per XCD
  const int i = x >> 3;                // 0..399 = b*25 + qt
  const int b = i / 25, qt = i - b * 25;
  const int qA = qt * 32;
  const bool hasB = (qA + 16 < NPIX);
  const int bh = b * NHEAD + h;

  const short* QpA = Q + ((size_t)bh * NPIX + qA + rr) * DPAD + qq * 8;
  const short* QpB = Q + ((size_t)bh * NPIX + (hasB ? qA + 16 : qA) + rr) * DPAD + qq * 8;
  const bf16x8 qfA0 = *(const bf16x8*)QpA;
  const bf16x8 qfA1 = *(const bf16x8*)(QpA + 32);
  const bf16x8 qfB0 = *(const bf16x8*)QpB;
  const bf16x8 qfB1 = *(const bf16x8*)(QpB + 32);

  const short* Kfp = Kf + (size_t)bh * (25 * 4 * 512) + lane * 8;
  const short* Vfp = Vf + (size_t)bh * (25 * 3 * 512) + lane * 8;
  const short* BpA = Bt3 + ((size_t)(h * 49 + 2 * qt) * 25) * 512 + lane * 8;
  const short* BpB = Bt3 + ((size_t)(h * 49 + (hasB ? 2 * qt + 1 : 2 * qt)) * 25) * 512 + lane * 8;
  short* sPA = sPbase + (w * 2 + 0) * 640;
  short* sPB = sPbase + (w * 2 + 1) * 640;

  const bf16x8 onesf = {(short)0x3F80, (short)0x3F80, (short)0x3F80, (short)0x3F80,
                        (short)0x3F80, (short)0x3F80, (short)0x3F80, (short)0x3F80};

  Chain cA, cB;
  cA.O0 = (f32x4){0.f,0.f,0.f,0.f}; cA.O1 = cA.O0; cA.O2 = cA.O0;
  cB.O0 = cA.O0; cB.O1 = cA.O0; cB.O2 = cA.O0;
  f32x4 spA = cA.O0, spB = cA.O0;

  const int cbeg = w * 6;
  const int cend = (w == 3) ? 25 : cbeg + 6;   // wave k-split: 6/6/6/7 chunks

  for (int c = cbeg; c < cend; ++c) {
    const uint4 bA = *(const uint4*)(BpA + (size_t)c * 512);
    const uint4 bB = *(const uint4*)(BpB + (size_t)c * 512);
    const short* kc = Kfp + (size_t)c * 2048;
    const bf16x8 ka0 = *(const bf16x8*)kc;
    const bf16x8 ka1 = *(const bf16x8*)(kc + 512);
    const bf16x8 kb0 = *(const bf16x8*)(kc + 1024);
    const bf16x8 kb1 = *(const bf16x8*)(kc + 1536);

    // bias as C-init (Bt3 layout == C-fragment layout), f32-exact
    f32x4 dA0 = (f32x4){blo(bA.x), bhi(bA.x), blo(bA.y), bhi(bA.y)};
    f32x4 dA1 = (f32x4){blo(bA.z), bhi(bA.z), blo(bA.w), bhi(bA.w)};
    f32x4 dB0 = (f32x4){blo(bB.x), bhi(bB.x), blo(bB.y), bhi(bB.y)};
    f32x4 dB1 = (f32x4){blo(bB.z), bhi(bB.z), blo(bB.w), bhi(bB.w)};

    __builtin_amdgcn_s_setprio(1);
    dA0 = __builtin_amdgcn_mfma_f32_16x16x32_bf16(ka0, qfA0, dA0, 0, 0, 0);
    dA0 = __builtin_amdgcn_mfma_f32_16x16x32_bf16(ka1, qfA1, dA0, 0, 0, 0);
    dB0 = __builtin_amdgcn_mfma_f32_16x16x32_bf16(ka0, qfB0, dB0, 0, 0, 0);
    dB0 = __builtin_amdgcn_mfma_f32_16x16x32_bf16(ka1, qfB1, dB0, 0, 0, 0);
    dA1 = __builtin_amdgcn_mfma_f32_16x16x32_bf16(kb0, qfA0, dA1, 0, 0, 0);
    dA1 = __builtin_amdgcn_mfma_f32_16x16x32_bf16(kb1, qfA1, dA1, 0, 0, 0);
    dB1 = __builtin_amdgcn_mfma_f32_16x16x32_bf16(kb0, qfB0, dB1, 0, 0, 0);
    dB1 = __builtin_amdgcn_mfma_f32_16x16x32_bf16(kb1, qfB1, dB1, 0, 0, 0);
    __builtin_amdgcn_s_setprio(0);

    store_p(dA0, dA1, sPA, rr, qq);
    store_p(dB0, dB1, sPB, rr, qq);

    const short* vc = Vfp + (size_t)c * 1536;
    const bf16x8 vf0 = *(const bf16x8*)vc;
    const bf16x8 vf1 = *(const bf16x8*)(vc + 512);
    const bf16x8 vf2 = *(const bf16x8*)(vc + 1024);
    const bf16x8 pfA = *(const bf16x8*)(sPA + rr * 40 + qq * 8);
    const bf16x8 pfB = *(const bf16x8*)(sPB + rr * 40 + qq * 8);
    __builtin_amdgcn_s_setprio(1);
    cA.O0 = __builtin_amdgcn_mfma_f32_16x16x32_bf16(vf0, pfA, cA.O0, 0, 0, 0);
    cA.O1 = __builtin_amdgcn_mfma_f32_16x16x32_bf16(vf1, pfA, cA.O1, 0, 0, 0);
    cA.O2 = __builtin_amdgcn_mfma_f32_16x16x32_bf16(vf2, pfA, cA.O2, 0, 0, 0);
    spA   = __builtin_amdgcn_mfma_f32_16x16x32_bf16(onesf, pfA, spA, 0, 0, 0);
    cB.O0 = __builtin_amdgcn_mfma_f32_16x16x32_bf16(vf0, pfB, cB.O0, 0, 0, 0);
    cB.O1 = __builtin_amdgcn_mfma_f32_16x16x32_bf16(vf1, pfB, cB.O1, 0, 0, 0);
    cB.O2 = __builtin_amdgcn_mfma_f32_16x16x32_bf16(vf2, pfB, cB.O2, 0, 0, 0);
    spB   = __builtin_amdgcn_mfma_f32_16x16x32_bf16(onesf, pfB, spB, 0, 0, 0);
    __builtin_amdgcn_s_setprio(0);
  }
  cA.sp = spA[0];                      // every row of ones-MFMA D = full k-sum for q=lane&15
  cB.sp = spB[0];

  // ---- cross-wave merge: plain lane-wise sums (no max -> no rescale) ----
  __syncthreads();
  float* mbuf = (float*)sMem;          // [j:13][wc:6][lane:64]
  if (w > 0) {
    const int col = ((w - 1) * 2 + 0) * 64 + lane;
    const int colB = col + 64;
    float vals[13] = {cA.O0[0], cA.O0[1], cA.O0[2], cA.O0[3],
                      cA.O1[0], cA.O1[1], cA.O1[2], cA.O1[3],
                      cA.O2[0], cA.O2[1], cA.O2[2], cA.O2[3], cA.sp};
    float valsB[13] = {cB.O0[0], cB.O0[1], cB.O0[2], cB.O0[3],
                       cB.O1[0], cB.O1[1], cB.O1[2], cB.O1[3],
                       cB.O2[0], cB.O2[1], cB.O2[2], cB.O2[3], cB.sp};
#pragma unroll
    for (int j = 0; j < 13; ++j) mbuf[j * 384 + col] = vals[j];
#pragma unroll
    for (int j = 0; j < 13; ++j) mbuf[j * 384 + colB] = valsB[j];
  }
  __syncthreads();
  if (w != 0) return;

#pragma unroll
  for (int ww = 0; ww < 3; ++ww) {
    const int col = (ww * 2 + 0) * 64 + lane;
    const int colB = col + 64;
#pragma unroll
    for (int j = 0; j < 4; ++j) {
      cA.O0[j] += mbuf[j * 384 + col];
      cA.O1[j] += mbuf[(4 + j) * 384 + col];
      cA.O2[j] += mbuf[(8 + j) * 384 + col];
      cB.O0[j] += mbuf[j * 384 + colB];
      cB.O1[j] += mbuf[(4 + j) * 384 + colB];
      cB.O2[j] += mbuf[(8 + j) * 384 + colB];
    }
    cA.sp += mbuf[12 * 384 + col];
    cB.sp += mbuf[12 * 384 + colB];
  }

  {
    const float invA = 1.f / cA.sp;    // sp already q-complete per lane (ones-MFMA)
    const f32x4 OA[3] = {cA.O0, cA.O1, cA.O2};
    short* base = AOf + ((size_t)(b * 49 + 2 * qt) * 12) * 512;
#pragma unroll
    for (int part = 0; part < 3; ++part) {
      const int ch = h * HDIM + part * 16 + qq * 4;
      uint2 pk;
      pk.x = pk_rne(OA[part][0] * invA, OA[part][1] * invA);
      pk.y = pk_rne(OA[part][2] * invA, OA[part][3] * invA);
      short* dst = base + (ch >> 5) * 512 + (rr + (((ch >> 3) & 3) << 4)) * 8 + (ch & 7);
      *(uint2*)dst = pk;
    }
  }
  if (hasB) {
    const float invB = 1.f / cB.sp;
    const f32x4 OB[3] = {cB.O0, cB.O1, cB.O2};
    short* base = AOf + ((size_t)(b * 49 + 2 * qt + 1) * 12) * 512;
#pragma unroll
    for (int part = 0; part < 3; ++part) {
      const int ch = h * HDIM + part * 16 + qq * 4;
      uint2 pk;
      pk.x = pk_rne(OB[part][0] * invB, OB[part][1] * invB);
      pk.y = pk_rne(OB[part][2] * invB, OB[part][3] * invB);
      short* dst = base + (ch >> 5) * 512 + (rr + (((ch >> 3) & 3) << 4)) * 8 + (ch & 7);
      *(uint2*)dst = pk;
    }
  }
}

// ================= proj GEMM (R9 shape: 2 mtiles x 7 pg = 14 accs, frag loads) ==========
__global__ __launch_bounds__(128) void proj_gemm(
    const short* __restrict__ Wfp, const float* __restrict__ pb,
    const short* __restrict__ AOf, float* __restrict__ out)
{
  const int t = threadIdx.x;
  const int w = t >> 6, lane = t & 63;     // w in {0,1}
  const int rr = lane & 15, qq = lane >> 4;
  const int ct = blockIdx.x;               // 0..5 : 64-ch tile
  const int pt = blockIdx.y;               // 0..111
  const int b = pt / 7, pt7 = pt % 7;
  const int px0 = pt7 * 112;

  const short* Ap0 = Wfp + ((size_t)(ct * 4 + 2 * w) * 12) * 512 + lane * 8;
  const short* Ap1 = Ap0 + 12 * 512;
  const short* Xp[7];
#pragma unroll
  for (int pg = 0; pg < 7; ++pg)
    Xp[pg] = AOf + ((size_t)(b * 49 + pt7 * 7 + pg) * 12) * 512 + lane * 8;

  f32x4 acc[2][7];
#pragma unroll
  for (int mi = 0; mi < 2; ++mi)
#pragma unroll
    for (int pg = 0; pg < 7; ++pg) acc[mi][pg] = (f32x4){0.f, 0.f, 0.f, 0.f};

  bf16x8 a0c = *(const bf16x8*)(Ap0);
  bf16x8 a1c = *(const bf16x8*)(Ap1);
  bf16x8 bcur[7];
#pragma unroll
  for (int pg = 0; pg < 7; ++pg) bcur[pg] = *(const bf16x8*)(Xp[pg]);

#pragma unroll 2
  for (int s = 0; s < 12; ++s) {
    const int sn = s + (s < 11 ? 1 : 0);
    const bf16x8 a0n = *(const bf16x8*)(Ap0 + (size_t)sn * 512);
    const bf16x8 a1n = *(const bf16x8*)(Ap1 + (size_t)sn * 512);
    bf16x8 bnxt[7];
#pragma unroll
    for (int pg = 0; pg < 7; ++pg) bnxt[pg] = *(const bf16x8*)(Xp[pg] + (size_t)sn * 512);

#pragma unroll
    for (int pg = 0; pg < 7; ++pg) {
      acc[0][pg] = __builtin_amdgcn_mfma_f32_16x16x32_bf16(a0c, bcur[pg], acc[0][pg], 0, 0, 0);
      acc[1][pg] = __builtin_amdgcn_mfma_f32_16x16x32_bf16(a1c, bcur[pg], acc[1][pg], 0, 0, 0);
    }
    a0c = a0n; a1c = a1n;
#pragma unroll
    for (int pg = 0; pg < 7; ++pg) bcur[pg] = bnxt[pg];
  }

#pragma unroll
  for (int mi = 0; mi < 2; ++mi) {
    const int ch0 = ct * 64 + (2 * w + mi) * 16 + qq * 4;
    const float4 bv = *(const float4*)(pb + ch0);
#pragma unroll
    for (int pg = 0; pg < 7; ++pg) {
      const int px = px0 + pg * 16 + rr;
      float* o = out + ((size_t)b * DIMC + ch0) * NPIX + px;
      o[0] = acc[mi][pg][0] + bv.x;
      o[NPIX] = acc[mi][pg][1] + bv.y;
      o[2 * NPIX] = acc[mi][pg][2] + bv.z;
      o[3 * NPIX] = acc[mi][pg][3] + bv.w;
    }
  }
}

extern "C" void kernel_launch(void* const* d_in, const int* in_sizes, int n_in,
                              void* d_out, int out_size, void* d_ws, size_t ws_size,
                              hipStream_t stream)
{
  const float* ll     = (const float*)d_in[0];
  const float* ha     = (const float*)d_in[1];
  const float* q_w    = (const float*)d_in[2];
  const float* q_b    = (const float*)d_in[3];
  const float* kv_w   = (const float*)d_in[4];
  const float* kv_b   = (const float*)d_in[5];
  const float* proj_w = (const float*)d_in[6];
  const float* proj_b = (const float*)d_in[7];
  const float* biases = (const float*)d_in[8];
  // d_in[9] (bias_idxs) unused: index == |i1-i2|*28+|j1-j2| (validated R1/R2)
  float* out = (float*)d_out;

  short* Qb  = (short*)d_ws;                          // 16*8*784*64   = 6,422,528
  short* Kf  = Qb  + (size_t)NB * NHEAD * NPIX * DPAD;
  short* Vf  = Kf  + (size_t)128 * 25 * 4 * 512;      //               = 6,553,600
  short* Xll = Vf  + (size_t)128 * 25 * 3 * 512;      //               = 4,915,200
  short* Xha = Xll + (size_t)NB * 49 * 12 * 512;      //               = 4,816,896
  short* AOf = Xha + (size_t)NB * 49 * 12 * 512;
  short* Bt3 = AOf + (size_t)NB * 49 * 12 * 512;
  short* Wf2 = Bt3 + (size_t)NHEAD * 49 * 25 * 512;   //               = 5,017,600
  short* Wfp = Wf2 + (size_t)55296 * 8;

  prep_kernel<<<dim3(4480), 256, 0, stream>>>(ll, ha, q_w, kv_w, proj_w, biases,
                                              Xll, Xha, Wf2, Wfp, Bt3, Qb, Kf, Vf);
  qkv_tiled<<<dim3(9, 112), 256, 0, stream>>>(Wf2, q_b, kv_b, Xll, Xha, Qb, Kf, Vf);
  attn_kernel<<<dim3(3200), 256, 0, stream>>>(Qb, Kf, Vf, Bt3, AOf);
  proj_gemm<<<dim3(6, 112), 128, 0, stream>>>(Wfp, proj_b, AOf, out);
}